// Round 1
// baseline (756.282 us; speedup 1.0000x reference)
//
#include <hip/hip_runtime.h>

// GCN: 2x GCNConv(128->128) + mean-pool + MLP(128->128->2), fp32.
// Strategy: build dest-sorted CSR each launch (no big float atomics),
// node-centric aggregation (1 wave/node, float2/lane), register-tiled fp32 GEMM.

__global__ void k_init(float* deg, int* counts, int* cursor, int N) {
    int i = blockIdx.x * blockDim.x + threadIdx.x;
    if (i < N) { deg[i] = 1.0f; counts[i] = 0; cursor[i] = 0; }  // self-loop weight 1
}

__global__ void k_deg_hist(const int* __restrict__ col, const float* __restrict__ ew,
                           float* deg, int* counts, int E) {
    int e = blockIdx.x * blockDim.x + threadIdx.x;
    if (e < E) {
        int c = col[e];
        atomicAdd(&deg[c], ew[e]);
        atomicAdd(&counts[c], 1);
    }
}

__global__ void k_dinv(const float* __restrict__ deg, float* dinv, int N) {
    int i = blockIdx.x * blockDim.x + threadIdx.x;
    if (i < N) { float d = deg[i]; dinv[i] = d > 0.f ? rsqrtf(d) : 0.f; }
}

// --- 3-kernel exclusive scan over counts[N] -> offs[N+1] ---
__global__ void k_scan1(const int* __restrict__ counts, int* __restrict__ offs,
                        int* __restrict__ bsums, int N) {
    __shared__ int lds[256];
    int t = threadIdx.x;
    int base = blockIdx.x * 1024 + t * 4;
    int a0 = 0, a1 = 0, a2 = 0, a3 = 0;
    if (base + 3 < N) {
        int4 v = *(const int4*)(counts + base);
        a0 = v.x; a1 = v.y; a2 = v.z; a3 = v.w;
    } else {
        if (base + 0 < N) a0 = counts[base + 0];
        if (base + 1 < N) a1 = counts[base + 1];
        if (base + 2 < N) a2 = counts[base + 2];
        if (base + 3 < N) a3 = counts[base + 3];
    }
    int tsum = a0 + a1 + a2 + a3;
    lds[t] = tsum;
    __syncthreads();
    for (int d = 1; d < 256; d <<= 1) {
        int v = (t >= d) ? lds[t - d] : 0;
        __syncthreads();
        lds[t] += v;
        __syncthreads();
    }
    int excl = lds[t] - tsum;
    if (base + 0 < N) offs[base + 0] = excl;
    if (base + 1 < N) offs[base + 1] = excl + a0;
    if (base + 2 < N) offs[base + 2] = excl + a0 + a1;
    if (base + 3 < N) offs[base + 3] = excl + a0 + a1 + a2;
    if (t == 255) bsums[blockIdx.x] = lds[255];
}

__global__ void k_scan2(int* bsums, int* offs, int nb, int N) {
    if (threadIdx.x == 0 && blockIdx.x == 0) {
        int run = 0;
        for (int i = 0; i < nb; ++i) { int v = bsums[i]; bsums[i] = run; run += v; }
        offs[N] = run;
    }
}

__global__ void k_scan3(int* offs, const int* __restrict__ bsums, int N) {
    int i = blockIdx.x * blockDim.x + threadIdx.x;
    if (i < N) offs[i] += bsums[i >> 10];
}

__global__ void k_scatter(const int* __restrict__ row, const int* __restrict__ col,
                          const float* __restrict__ ew, const float* __restrict__ dinv,
                          const int* __restrict__ offs, int* cursor,
                          int* __restrict__ csr_src, float* __restrict__ csr_w, int E) {
    int e = blockIdx.x * blockDim.x + threadIdx.x;
    if (e < E) {
        int r = row[e], c = col[e];
        float w = dinv[r] * ew[e] * dinv[c];
        int pos = offs[c] + atomicAdd(&cursor[c], 1);
        csr_src[pos] = r;
        csr_w[pos] = w;
    }
}

// Y[n][o] = sum_k X[n][k] * W[o][k]   (h = x @ W.T), fp32 vector ALU.
// Block: 256 thr = 16 og x 16 ng; thread tile 4 nodes x 8 outs; k-step float4.
__global__ __launch_bounds__(256) void k_gemm(const float* __restrict__ X,
                                              const float* __restrict__ W,
                                              float* __restrict__ Y, int N) {
    int t = threadIdx.x;
    int og = t & 15;
    int ng = t >> 4;
    int nbase = blockIdx.x * 64 + ng * 4;
    int ob = og * 8;
    float acc[4][8];
#pragma unroll
    for (int i = 0; i < 4; ++i)
#pragma unroll
        for (int j = 0; j < 8; ++j) acc[i][j] = 0.f;
    bool v[4];
#pragma unroll
    for (int i = 0; i < 4; ++i) v[i] = (nbase + i) < N;

    for (int k = 0; k < 128; k += 4) {
        float4 xv[4];
#pragma unroll
        for (int i = 0; i < 4; ++i)
            xv[i] = v[i] ? *(const float4*)(X + (size_t)(nbase + i) * 128 + k)
                         : make_float4(0.f, 0.f, 0.f, 0.f);
        float4 wv[8];
#pragma unroll
        for (int j = 0; j < 8; ++j)
            wv[j] = *(const float4*)(W + (size_t)(ob + j) * 128 + k);
#pragma unroll
        for (int i = 0; i < 4; ++i)
#pragma unroll
            for (int j = 0; j < 8; ++j)
                acc[i][j] += xv[i].x * wv[j].x + xv[i].y * wv[j].y +
                             xv[i].z * wv[j].z + xv[i].w * wv[j].w;
    }
#pragma unroll
    for (int i = 0; i < 4; ++i) {
        if (v[i]) {
            float* dst = Y + (size_t)(nbase + i) * 128 + ob;
            *(float4*)dst       = make_float4(acc[i][0], acc[i][1], acc[i][2], acc[i][3]);
            *(float4*)(dst + 4) = make_float4(acc[i][4], acc[i][5], acc[i][6], acc[i][7]);
    }
    }
}

// One wave per node: O[i] = relu(bias + dinv[i]^2*H[i] + sum_e w_e * H[src_e]).
__global__ __launch_bounds__(256) void k_agg(const float* __restrict__ H, float* __restrict__ O,
                                             const int* __restrict__ offs,
                                             const int* __restrict__ csr_src,
                                             const float* __restrict__ csr_w,
                                             const float* __restrict__ dinv,
                                             const float* __restrict__ bias, int N) {
    int wid = (blockIdx.x * blockDim.x + threadIdx.x) >> 6;
    int lane = threadIdx.x & 63;
    if (wid >= N) return;
    const float2* H2 = (const float2*)H;
    float di = dinv[wid];
    float sw = di * di;
    float2 h0 = H2[(size_t)wid * 64 + lane];
    float ax = sw * h0.x, ay = sw * h0.y;
    int s = offs[wid], e = offs[wid + 1];
    for (int j = s; j < e; j += 64) {
        int idx = j + lane;
        int src = 0; float w = 0.f;
        if (idx < e) { src = csr_src[idx]; w = csr_w[idx]; }
        int cnt = min(64, e - j);
        for (int k = 0; k < cnt; ++k) {
            int   ss = __shfl(src, k, 64);
            float ww = __shfl(w, k, 64);
            float2 hv = H2[(size_t)ss * 64 + lane];
            ax += ww * hv.x;
            ay += ww * hv.y;
        }
    }
    float2 bb = ((const float2*)bias)[lane];
    ax = fmaxf(ax + bb.x, 0.f);
    ay = fmaxf(ay + bb.y, 0.f);
    ((float2*)O)[(size_t)wid * 64 + lane] = make_float2(ax, ay);
}

// One block per graph: mean-pool (batch sorted -> binary search) then MLP.
__global__ __launch_bounds__(128) void k_pool_mlp(const float* __restrict__ H,
                                                  const int* __restrict__ batch,
                                                  const float* __restrict__ w1,
                                                  const float* __restrict__ b1,
                                                  const float* __restrict__ w2,
                                                  const float* __restrict__ b2,
                                                  float* __restrict__ out, int N, int G) {
    __shared__ float pooled[128];
    __shared__ float h1[128];
    int g = blockIdx.x, t = threadIdx.x;
    int lo = 0, hi = N;
    while (lo < hi) { int m = (lo + hi) >> 1; if (batch[m] < g) lo = m + 1; else hi = m; }
    int s = lo;
    lo = s; hi = N;
    while (lo < hi) { int m = (lo + hi) >> 1; if (batch[m] < g + 1) lo = m + 1; else hi = m; }
    int ep = lo;
    float acc = 0.f;
    for (int n = s; n < ep; ++n) acc += H[(size_t)n * 128 + t];
    float cnt = (float)(ep - s);
    pooled[t] = acc / fmaxf(cnt, 1.0f);
    __syncthreads();
    float sum = b1[t];
#pragma unroll 4
    for (int k = 0; k < 128; ++k) sum += w1[t * 128 + k] * pooled[k];
    h1[t] = fmaxf(sum, 0.f);
    __syncthreads();
    if (t < 2) {
        float s2 = b2[t];
        for (int k = 0; k < 128; ++k) s2 += w2[t * 128 + k] * h1[k];
        out[g * 2 + t] = s2;
    }
}

extern "C" void kernel_launch(void* const* d_in, const int* in_sizes, int n_in,
                              void* d_out, int out_size, void* d_ws, size_t ws_size,
                              hipStream_t stream) {
    const float* x   = (const float*)d_in[0];
    const int*   ei  = (const int*)d_in[1];
    const float* ew  = (const float*)d_in[2];
    const int* batch = (const int*)d_in[3];
    const float* W1  = (const float*)d_in[4];
    const float* b1  = (const float*)d_in[5];
    const float* W2  = (const float*)d_in[6];
    const float* b2  = (const float*)d_in[7];
    const float* l1w = (const float*)d_in[8];
    const float* l1b = (const float*)d_in[9];
    const float* l2w = (const float*)d_in[10];
    const float* l2b = (const float*)d_in[11];
    float* out = (float*)d_out;

    const int E = in_sizes[2];   // edge_weight count
    const int N = in_sizes[3];   // batch count = nodes
    const int G = out_size / 2;
    const int* row = ei;
    const int* col = ei + E;

    char* p = (char*)d_ws;
    auto alloc = [&](size_t bytes) -> void* {
        void* r = (void*)p;
        p += (bytes + 255) & ~(size_t)255;
        return r;
    };
    float* deg    = (float*)alloc((size_t)N * 4);
    float* dinv   = (float*)alloc((size_t)N * 4);
    int*   counts = (int*)alloc((size_t)N * 4);
    int*   cursor = (int*)alloc((size_t)N * 4);
    int*   offs   = (int*)alloc((size_t)(N + 1) * 4);
    int*   bsums  = (int*)alloc(256 * 4);
    int*   csr_src= (int*)alloc((size_t)E * 4);
    float* csr_w  = (float*)alloc((size_t)E * 4);
    float* hbuf   = (float*)alloc((size_t)N * 128 * 4);
    float* abuf   = (float*)alloc((size_t)N * 128 * 4);

    int nbN = (N + 255) / 256;
    int nbE = (E + 255) / 256;
    k_init<<<nbN, 256, 0, stream>>>(deg, counts, cursor, N);
    k_deg_hist<<<nbE, 256, 0, stream>>>(col, ew, deg, counts, E);
    k_dinv<<<nbN, 256, 0, stream>>>(deg, dinv, N);
    int sb = (N + 1023) / 1024;
    k_scan1<<<sb, 256, 0, stream>>>(counts, offs, bsums, N);
    k_scan2<<<1, 64, 0, stream>>>(bsums, offs, sb, N);
    k_scan3<<<nbN, 256, 0, stream>>>(offs, bsums, N);
    k_scatter<<<nbE, 256, 0, stream>>>(row, col, ew, dinv, offs, cursor, csr_src, csr_w, E);

    int gb = (N + 63) / 64;
    int ab = ((size_t)N * 64 + 255) / 256;
    k_gemm<<<gb, 256, 0, stream>>>(x, W1, hbuf, N);
    k_agg<<<ab, 256, 0, stream>>>(hbuf, abuf, offs, csr_src, csr_w, dinv, b1, N);
    k_gemm<<<gb, 256, 0, stream>>>(abuf, W2, hbuf, N);
    k_agg<<<ab, 256, 0, stream>>>(hbuf, abuf, offs, csr_src, csr_w, dinv, b2, N);
    k_pool_mlp<<<G, 128, 0, stream>>>(abuf, batch, l1w, l1b, l2w, l2b, out, N, G);
}

// Round 2
// 643.850 us; speedup vs baseline: 1.1746x; 1.1746x over previous
//
#include <hip/hip_runtime.h>

// GCN: 2x GCNConv(128->128) + mean-pool + MLP(128->128->2), fp32.
// R1: k_gemm rewritten — W staged in LDS (64 KB), 64 nodes x 128 outs per
// block, 4x8 thread tile. Rest unchanged from R0 for attribution.

__global__ void k_init(float* deg, int* counts, int* cursor, int N) {
    int i = blockIdx.x * blockDim.x + threadIdx.x;
    if (i < N) { deg[i] = 1.0f; counts[i] = 0; cursor[i] = 0; }  // self-loop weight 1
}

__global__ void k_deg_hist(const int* __restrict__ col, const float* __restrict__ ew,
                           float* deg, int* counts, int E) {
    int e = blockIdx.x * blockDim.x + threadIdx.x;
    if (e < E) {
        int c = col[e];
        atomicAdd(&deg[c], ew[e]);
        atomicAdd(&counts[c], 1);
    }
}

__global__ void k_dinv(const float* __restrict__ deg, float* dinv, int N) {
    int i = blockIdx.x * blockDim.x + threadIdx.x;
    if (i < N) { float d = deg[i]; dinv[i] = d > 0.f ? rsqrtf(d) : 0.f; }
}

// --- 3-kernel exclusive scan over counts[N] -> offs[N+1] ---
__global__ void k_scan1(const int* __restrict__ counts, int* __restrict__ offs,
                        int* __restrict__ bsums, int N) {
    __shared__ int lds[256];
    int t = threadIdx.x;
    int base = blockIdx.x * 1024 + t * 4;
    int a0 = 0, a1 = 0, a2 = 0, a3 = 0;
    if (base + 3 < N) {
        int4 v = *(const int4*)(counts + base);
        a0 = v.x; a1 = v.y; a2 = v.z; a3 = v.w;
    } else {
        if (base + 0 < N) a0 = counts[base + 0];
        if (base + 1 < N) a1 = counts[base + 1];
        if (base + 2 < N) a2 = counts[base + 2];
        if (base + 3 < N) a3 = counts[base + 3];
    }
    int tsum = a0 + a1 + a2 + a3;
    lds[t] = tsum;
    __syncthreads();
    for (int d = 1; d < 256; d <<= 1) {
        int v = (t >= d) ? lds[t - d] : 0;
        __syncthreads();
        lds[t] += v;
        __syncthreads();
    }
    int excl = lds[t] - tsum;
    if (base + 0 < N) offs[base + 0] = excl;
    if (base + 1 < N) offs[base + 1] = excl + a0;
    if (base + 2 < N) offs[base + 2] = excl + a0 + a1;
    if (base + 3 < N) offs[base + 3] = excl + a0 + a1 + a2;
    if (t == 255) bsums[blockIdx.x] = lds[255];
}

__global__ void k_scan2(int* bsums, int* offs, int nb, int N) {
    if (threadIdx.x == 0 && blockIdx.x == 0) {
        int run = 0;
        for (int i = 0; i < nb; ++i) { int v = bsums[i]; bsums[i] = run; run += v; }
        offs[N] = run;
    }
}

__global__ void k_scan3(int* offs, const int* __restrict__ bsums, int N) {
    int i = blockIdx.x * blockDim.x + threadIdx.x;
    if (i < N) offs[i] += bsums[i >> 10];
}

__global__ void k_scatter(const int* __restrict__ row, const int* __restrict__ col,
                          const float* __restrict__ ew, const float* __restrict__ dinv,
                          const int* __restrict__ offs, int* cursor,
                          int* __restrict__ csr_src, float* __restrict__ csr_w, int E) {
    int e = blockIdx.x * blockDim.x + threadIdx.x;
    if (e < E) {
        int r = row[e], c = col[e];
        float w = dinv[r] * ew[e] * dinv[c];
        int pos = offs[c] + atomicAdd(&cursor[c], 1);
        csr_src[pos] = r;
        csr_w[pos] = w;
    }
}

// Y[n][o] = sum_k X[n][k] * W[o][k]   (h = x @ W.T), fp32 vector ALU.
// W (128x128 = 64 KB) staged in LDS. Block 256 thr = 16 out-groups (t>>4,
// 8 outs) x 16 node-groups (t&15, 4 nodes) -> 64 nodes x 128 outs per block.
// 4-way LDS bank broadcast-conflict on sW reads (row stride 128 % 32 == 0,
// 4 distinct og rows/wave) costs 1.58x on LDS pipe — stays under VALU cost.
__global__ __launch_bounds__(256, 2) void k_gemm(const float* __restrict__ X,
                                                 const float* __restrict__ W,
                                                 float* __restrict__ Y, int N) {
    __shared__ float sW[128 * 128];
    int t = threadIdx.x;
    // stage W: 16384 floats = 4096 float4 / 256 thr = 16 float4 each
    {
        const float4* src = (const float4*)W;
        float4* dst = (float4*)sW;
#pragma unroll
        for (int i = 0; i < 16; ++i)
            dst[t + 256 * i] = src[t + 256 * i];
    }
    __syncthreads();

    int og = t >> 4;          // 0..15 -> 8 outs each
    int ng = t & 15;          // 0..15 -> 4 nodes each
    int nbase = blockIdx.x * 64 + ng * 4;
    int ob = og * 8;
    float acc[4][8];
#pragma unroll
    for (int i = 0; i < 4; ++i)
#pragma unroll
        for (int j = 0; j < 8; ++j) acc[i][j] = 0.f;
    bool v[4];
#pragma unroll
    for (int i = 0; i < 4; ++i) v[i] = (nbase + i) < N;

#pragma unroll 2
    for (int k = 0; k < 128; k += 4) {
        float4 xv[4];
#pragma unroll
        for (int i = 0; i < 4; ++i)
            xv[i] = v[i] ? *(const float4*)(X + (size_t)(nbase + i) * 128 + k)
                         : make_float4(0.f, 0.f, 0.f, 0.f);
        float4 wv[8];
#pragma unroll
        for (int j = 0; j < 8; ++j)
            wv[j] = *(const float4*)(sW + (ob + j) * 128 + k);
#pragma unroll
        for (int i = 0; i < 4; ++i)
#pragma unroll
            for (int j = 0; j < 8; ++j)
                acc[i][j] += xv[i].x * wv[j].x + xv[i].y * wv[j].y +
                             xv[i].z * wv[j].z + xv[i].w * wv[j].w;
    }
#pragma unroll
    for (int i = 0; i < 4; ++i) {
        if (v[i]) {
            float* dst = Y + (size_t)(nbase + i) * 128 + ob;
            *(float4*)dst       = make_float4(acc[i][0], acc[i][1], acc[i][2], acc[i][3]);
            *(float4*)(dst + 4) = make_float4(acc[i][4], acc[i][5], acc[i][6], acc[i][7]);
        }
    }
}

// One wave per node: O[i] = relu(bias + dinv[i]^2*H[i] + sum_e w_e * H[src_e]).
__global__ __launch_bounds__(256) void k_agg(const float* __restrict__ H, float* __restrict__ O,
                                             const int* __restrict__ offs,
                                             const int* __restrict__ csr_src,
                                             const float* __restrict__ csr_w,
                                             const float* __restrict__ dinv,
                                             const float* __restrict__ bias, int N) {
    int wid = (blockIdx.x * blockDim.x + threadIdx.x) >> 6;
    int lane = threadIdx.x & 63;
    if (wid >= N) return;
    const float2* H2 = (const float2*)H;
    float di = dinv[wid];
    float sw = di * di;
    float2 h0 = H2[(size_t)wid * 64 + lane];
    float ax = sw * h0.x, ay = sw * h0.y;
    int s = offs[wid], e = offs[wid + 1];
    for (int j = s; j < e; j += 64) {
        int idx = j + lane;
        int src = 0; float w = 0.f;
        if (idx < e) { src = csr_src[idx]; w = csr_w[idx]; }
        int cnt = min(64, e - j);
        for (int k = 0; k < cnt; ++k) {
            int   ss = __shfl(src, k, 64);
            float ww = __shfl(w, k, 64);
            float2 hv = H2[(size_t)ss * 64 + lane];
            ax += ww * hv.x;
            ay += ww * hv.y;
        }
    }
    float2 bb = ((const float2*)bias)[lane];
    ax = fmaxf(ax + bb.x, 0.f);
    ay = fmaxf(ay + bb.y, 0.f);
    ((float2*)O)[(size_t)wid * 64 + lane] = make_float2(ax, ay);
}

// One block per graph: mean-pool (batch sorted -> binary search) then MLP.
__global__ __launch_bounds__(128) void k_pool_mlp(const float* __restrict__ H,
                                                  const int* __restrict__ batch,
                                                  const float* __restrict__ w1,
                                                  const float* __restrict__ b1,
                                                  const float* __restrict__ w2,
                                                  const float* __restrict__ b2,
                                                  float* __restrict__ out, int N, int G) {
    __shared__ float pooled[128];
    __shared__ float h1[128];
    int g = blockIdx.x, t = threadIdx.x;
    int lo = 0, hi = N;
    while (lo < hi) { int m = (lo + hi) >> 1; if (batch[m] < g) lo = m + 1; else hi = m; }
    int s = lo;
    lo = s; hi = N;
    while (lo < hi) { int m = (lo + hi) >> 1; if (batch[m] < g + 1) lo = m + 1; else hi = m; }
    int ep = lo;
    float acc = 0.f;
    for (int n = s; n < ep; ++n) acc += H[(size_t)n * 128 + t];
    float cnt = (float)(ep - s);
    pooled[t] = acc / fmaxf(cnt, 1.0f);
    __syncthreads();
    float sum = b1[t];
#pragma unroll 4
    for (int k = 0; k < 128; ++k) sum += w1[t * 128 + k] * pooled[k];
    h1[t] = fmaxf(sum, 0.f);
    __syncthreads();
    if (t < 2) {
        float s2 = b2[t];
        for (int k = 0; k < 128; ++k) s2 += w2[t * 128 + k] * h1[k];
        out[g * 2 + t] = s2;
    }
}

extern "C" void kernel_launch(void* const* d_in, const int* in_sizes, int n_in,
                              void* d_out, int out_size, void* d_ws, size_t ws_size,
                              hipStream_t stream) {
    const float* x   = (const float*)d_in[0];
    const int*   ei  = (const int*)d_in[1];
    const float* ew  = (const float*)d_in[2];
    const int* batch = (const int*)d_in[3];
    const float* W1  = (const float*)d_in[4];
    const float* b1  = (const float*)d_in[5];
    const float* W2  = (const float*)d_in[6];
    const float* b2  = (const float*)d_in[7];
    const float* l1w = (const float*)d_in[8];
    const float* l1b = (const float*)d_in[9];
    const float* l2w = (const float*)d_in[10];
    const float* l2b = (const float*)d_in[11];
    float* out = (float*)d_out;

    const int E = in_sizes[2];   // edge_weight count
    const int N = in_sizes[3];   // batch count = nodes
    const int G = out_size / 2;
    const int* row = ei;
    const int* col = ei + E;

    char* p = (char*)d_ws;
    auto alloc = [&](size_t bytes) -> void* {
        void* r = (void*)p;
        p += (bytes + 255) & ~(size_t)255;
        return r;
    };
    float* deg    = (float*)alloc((size_t)N * 4);
    float* dinv   = (float*)alloc((size_t)N * 4);
    int*   counts = (int*)alloc((size_t)N * 4);
    int*   cursor = (int*)alloc((size_t)N * 4);
    int*   offs   = (int*)alloc((size_t)(N + 1) * 4);
    int*   bsums  = (int*)alloc(256 * 4);
    int*   csr_src= (int*)alloc((size_t)E * 4);
    float* csr_w  = (float*)alloc((size_t)E * 4);
    float* hbuf   = (float*)alloc((size_t)N * 128 * 4);
    float* abuf   = (float*)alloc((size_t)N * 128 * 4);

    int nbN = (N + 255) / 256;
    int nbE = (E + 255) / 256;
    k_init<<<nbN, 256, 0, stream>>>(deg, counts, cursor, N);
    k_deg_hist<<<nbE, 256, 0, stream>>>(col, ew, deg, counts, E);
    k_dinv<<<nbN, 256, 0, stream>>>(deg, dinv, N);
    int sb = (N + 1023) / 1024;
    k_scan1<<<sb, 256, 0, stream>>>(counts, offs, bsums, N);
    k_scan2<<<1, 64, 0, stream>>>(bsums, offs, sb, N);
    k_scan3<<<nbN, 256, 0, stream>>>(offs, bsums, N);
    k_scatter<<<nbE, 256, 0, stream>>>(row, col, ew, dinv, offs, cursor, csr_src, csr_w, E);

    int gb = (N + 63) / 64;
    int ab = ((size_t)N * 64 + 255) / 256;
    k_gemm<<<gb, 256, 0, stream>>>(x, W1, hbuf, N);
    k_agg<<<ab, 256, 0, stream>>>(hbuf, abuf, offs, csr_src, csr_w, dinv, b1, N);
    k_gemm<<<gb, 256, 0, stream>>>(abuf, W2, hbuf, N);
    k_agg<<<ab, 256, 0, stream>>>(hbuf, abuf, offs, csr_src, csr_w, dinv, b2, N);
    k_pool_mlp<<<G, 128, 0, stream>>>(abuf, batch, l1w, l1b, l2w, l2b, out, N, G);
}

// Round 3
// 517.599 us; speedup vs baseline: 1.4611x; 1.2439x over previous
//
#include <hip/hip_runtime.h>

// GCN: 2x GCNConv(128->128) + mean-pool + MLP(128->128->2), fp32.
// R2: k_agg rewritten — wave-uniform scalar CSR loads (no shfl), 4x-unrolled
// gathers for memory-level parallelism. Pool+MLP split: parallel k_pool
// (atomicAdd partial sums) + tiny k_mlp. Workspace 512B-aligned.

__global__ void k_init(float* deg, int* counts, int* cursor, int N,
                       float* pooled, int M) {
    int i = blockIdx.x * blockDim.x + threadIdx.x;
    if (i < N) { deg[i] = 1.0f; counts[i] = 0; cursor[i] = 0; }  // self-loop weight 1
    if (i < M) pooled[i] = 0.f;
}

__global__ void k_deg_hist(const int* __restrict__ col, const float* __restrict__ ew,
                           float* deg, int* counts, int E) {
    int e = blockIdx.x * blockDim.x + threadIdx.x;
    if (e < E) {
        int c = col[e];
        atomicAdd(&deg[c], ew[e]);
        atomicAdd(&counts[c], 1);
    }
}

__global__ void k_dinv(const float* __restrict__ deg, float* dinv, int N) {
    int i = blockIdx.x * blockDim.x + threadIdx.x;
    if (i < N) { float d = deg[i]; dinv[i] = d > 0.f ? rsqrtf(d) : 0.f; }
}

// --- 3-kernel exclusive scan over counts[N] -> offs[N+1] ---
__global__ void k_scan1(const int* __restrict__ counts, int* __restrict__ offs,
                        int* __restrict__ bsums, int N) {
    __shared__ int lds[256];
    int t = threadIdx.x;
    int base = blockIdx.x * 1024 + t * 4;
    int a0 = 0, a1 = 0, a2 = 0, a3 = 0;
    if (base + 3 < N) {
        int4 v = *(const int4*)(counts + base);
        a0 = v.x; a1 = v.y; a2 = v.z; a3 = v.w;
    } else {
        if (base + 0 < N) a0 = counts[base + 0];
        if (base + 1 < N) a1 = counts[base + 1];
        if (base + 2 < N) a2 = counts[base + 2];
        if (base + 3 < N) a3 = counts[base + 3];
    }
    int tsum = a0 + a1 + a2 + a3;
    lds[t] = tsum;
    __syncthreads();
    for (int d = 1; d < 256; d <<= 1) {
        int v = (t >= d) ? lds[t - d] : 0;
        __syncthreads();
        lds[t] += v;
        __syncthreads();
    }
    int excl = lds[t] - tsum;
    if (base + 0 < N) offs[base + 0] = excl;
    if (base + 1 < N) offs[base + 1] = excl + a0;
    if (base + 2 < N) offs[base + 2] = excl + a0 + a1;
    if (base + 3 < N) offs[base + 3] = excl + a0 + a1 + a2;
    if (t == 255) bsums[blockIdx.x] = lds[255];
}

__global__ void k_scan2(int* bsums, int* offs, int nb, int N) {
    if (threadIdx.x == 0 && blockIdx.x == 0) {
        int run = 0;
        for (int i = 0; i < nb; ++i) { int v = bsums[i]; bsums[i] = run; run += v; }
        offs[N] = run;
    }
}

__global__ void k_scan3(int* offs, const int* __restrict__ bsums, int N) {
    int i = blockIdx.x * blockDim.x + threadIdx.x;
    if (i < N) offs[i] += bsums[i >> 10];
}

__global__ void k_scatter(const int* __restrict__ row, const int* __restrict__ col,
                          const float* __restrict__ ew, const float* __restrict__ dinv,
                          const int* __restrict__ offs, int* cursor,
                          int* __restrict__ csr_src, float* __restrict__ csr_w, int E) {
    int e = blockIdx.x * blockDim.x + threadIdx.x;
    if (e < E) {
        int r = row[e], c = col[e];
        float w = dinv[r] * ew[e] * dinv[c];
        int pos = offs[c] + atomicAdd(&cursor[c], 1);
        csr_src[pos] = r;
        csr_w[pos] = w;
    }
}

// Y[n][o] = sum_k X[n][k] * W[o][k]   (h = x @ W.T), fp32 vector ALU, W in LDS.
__global__ __launch_bounds__(256, 2) void k_gemm(const float* __restrict__ X,
                                                 const float* __restrict__ W,
                                                 float* __restrict__ Y, int N) {
    __shared__ float sW[128 * 128];
    int t = threadIdx.x;
    {
        const float4* src = (const float4*)W;
        float4* dst = (float4*)sW;
#pragma unroll
        for (int i = 0; i < 16; ++i)
            dst[t + 256 * i] = src[t + 256 * i];
    }
    __syncthreads();

    int og = t >> 4;
    int ng = t & 15;
    int nbase = blockIdx.x * 64 + ng * 4;
    int ob = og * 8;
    float acc[4][8];
#pragma unroll
    for (int i = 0; i < 4; ++i)
#pragma unroll
        for (int j = 0; j < 8; ++j) acc[i][j] = 0.f;
    bool v[4];
#pragma unroll
    for (int i = 0; i < 4; ++i) v[i] = (nbase + i) < N;

#pragma unroll 2
    for (int k = 0; k < 128; k += 4) {
        float4 xv[4];
#pragma unroll
        for (int i = 0; i < 4; ++i)
            xv[i] = v[i] ? *(const float4*)(X + (size_t)(nbase + i) * 128 + k)
                         : make_float4(0.f, 0.f, 0.f, 0.f);
        float4 wv[8];
#pragma unroll
        for (int j = 0; j < 8; ++j)
            wv[j] = *(const float4*)(sW + (ob + j) * 128 + k);
#pragma unroll
        for (int i = 0; i < 4; ++i)
#pragma unroll
            for (int j = 0; j < 8; ++j)
                acc[i][j] += xv[i].x * wv[j].x + xv[i].y * wv[j].y +
                             xv[i].z * wv[j].z + xv[i].w * wv[j].w;
    }
#pragma unroll
    for (int i = 0; i < 4; ++i) {
        if (v[i]) {
            float* dst = Y + (size_t)(nbase + i) * 128 + ob;
            *(float4*)dst       = make_float4(acc[i][0], acc[i][1], acc[i][2], acc[i][3]);
            *(float4*)(dst + 4) = make_float4(acc[i][4], acc[i][5], acc[i][6], acc[i][7]);
        }
    }
}

// One wave per node. wid forced wave-uniform -> offs/csr reads become scalar
// (s_load) loads; edge loop unrolled 4x so 4 independent 512B gathers are in
// flight per wave. O[i] = relu(bias + dinv^2*H[i] + sum_e w_e * H[src_e]).
__global__ __launch_bounds__(256) void k_agg(const float* __restrict__ H, float* __restrict__ O,
                                             const int* __restrict__ offs,
                                             const int* __restrict__ csr_src,
                                             const float* __restrict__ csr_w,
                                             const float* __restrict__ dinv,
                                             const float* __restrict__ bias, int N) {
    int wid = __builtin_amdgcn_readfirstlane((blockIdx.x * blockDim.x + threadIdx.x) >> 6);
    int lane = threadIdx.x & 63;
    if (wid >= N) return;
    const float2* H2 = (const float2*)H;
    float di = dinv[wid];
    float sw = di * di;
    float2 h0 = H2[(size_t)wid * 64 + lane];
    float ax = sw * h0.x, ay = sw * h0.y;
    int s = offs[wid], e = offs[wid + 1];
    int j = s;
    for (; j + 4 <= e; j += 4) {
        int   s0 = csr_src[j],   s1 = csr_src[j+1], s2 = csr_src[j+2], s3 = csr_src[j+3];
        float w0 = csr_w[j],     w1 = csr_w[j+1],   w2 = csr_w[j+2],   w3 = csr_w[j+3];
        float2 a0 = H2[(size_t)s0 * 64 + lane];
        float2 a1 = H2[(size_t)s1 * 64 + lane];
        float2 a2 = H2[(size_t)s2 * 64 + lane];
        float2 a3 = H2[(size_t)s3 * 64 + lane];
        ax += w0 * a0.x; ay += w0 * a0.y;
        ax += w1 * a1.x; ay += w1 * a1.y;
        ax += w2 * a2.x; ay += w2 * a2.y;
        ax += w3 * a3.x; ay += w3 * a3.y;
    }
    for (; j < e; ++j) {
        int ss = csr_src[j];
        float ww = csr_w[j];
        float2 hv = H2[(size_t)ss * 64 + lane];
        ax += ww * hv.x; ay += ww * hv.y;
    }
    float2 bb = ((const float2*)bias)[lane];
    ax = fmaxf(ax + bb.x, 0.f);
    ay = fmaxf(ay + bb.y, 0.f);
    ((float2*)O)[(size_t)wid * 64 + lane] = make_float2(ax, ay);
}

// Parallel mean-pool stage 1: each block sums 64 consecutive (batch-sorted)
// nodes per feature column, run-accumulating per graph segment, then one
// atomicAdd per segment boundary into pooled[G][128].
__global__ __launch_bounds__(128) void k_pool(const float* __restrict__ H,
                                              const int* __restrict__ batch,
                                              float* __restrict__ pooled, int N) {
    int t = threadIdx.x;
    int n0 = blockIdx.x * 64;
    if (n0 >= N) return;
    int n1 = min(n0 + 64, N);
    int cur = batch[n0];
    float acc = 0.f;
    for (int n = n0; n < n1; ++n) {
        int g = batch[n];
        if (g != cur) {
            atomicAdd(&pooled[cur * 128 + t], acc);
            acc = 0.f; cur = g;
        }
        acc += H[(size_t)n * 128 + t];
    }
    atomicAdd(&pooled[cur * 128 + t], acc);
}

// Stage 2: divide by count (binary search over sorted batch) + MLP.
__global__ __launch_bounds__(128) void k_mlp(const float* __restrict__ pooled,
                                             const int* __restrict__ batch,
                                             const float* __restrict__ w1,
                                             const float* __restrict__ b1,
                                             const float* __restrict__ w2,
                                             const float* __restrict__ b2,
                                             float* __restrict__ out, int N, int G) {
    __shared__ float pl[128];
    __shared__ float h1[128];
    int g = blockIdx.x, t = threadIdx.x;
    int lo = 0, hi = N;
    while (lo < hi) { int m = (lo + hi) >> 1; if (batch[m] < g) lo = m + 1; else hi = m; }
    int s = lo;
    lo = s; hi = N;
    while (lo < hi) { int m = (lo + hi) >> 1; if (batch[m] < g + 1) lo = m + 1; else hi = m; }
    float cnt = (float)(lo - s);
    pl[t] = pooled[g * 128 + t] / fmaxf(cnt, 1.0f);
    __syncthreads();
    float sum = b1[t];
#pragma unroll 4
    for (int k = 0; k < 128; ++k) sum += w1[t * 128 + k] * pl[k];
    h1[t] = fmaxf(sum, 0.f);
    __syncthreads();
    if (t < 2) {
        float s2 = b2[t];
        for (int k = 0; k < 128; ++k) s2 += w2[t * 128 + k] * h1[k];
        out[g * 2 + t] = s2;
    }
}

extern "C" void kernel_launch(void* const* d_in, const int* in_sizes, int n_in,
                              void* d_out, int out_size, void* d_ws, size_t ws_size,
                              hipStream_t stream) {
    const float* x   = (const float*)d_in[0];
    const int*   ei  = (const int*)d_in[1];
    const float* ew  = (const float*)d_in[2];
    const int* batch = (const int*)d_in[3];
    const float* W1  = (const float*)d_in[4];
    const float* b1  = (const float*)d_in[5];
    const float* W2  = (const float*)d_in[6];
    const float* b2  = (const float*)d_in[7];
    const float* l1w = (const float*)d_in[8];
    const float* l1b = (const float*)d_in[9];
    const float* l2w = (const float*)d_in[10];
    const float* l2b = (const float*)d_in[11];
    float* out = (float*)d_out;

    const int E = in_sizes[2];   // edge_weight count
    const int N = in_sizes[3];   // batch count = nodes
    const int G = out_size / 2;
    const int* row = ei;
    const int* col = ei + E;

    char* p = (char*)d_ws;
    auto alloc = [&](size_t bytes) -> void* {
        void* r = (void*)p;
        p += (bytes + 511) & ~(size_t)511;
        return r;
    };
    float* deg    = (float*)alloc((size_t)N * 4);
    float* dinv   = (float*)alloc((size_t)N * 4);
    int*   counts = (int*)alloc((size_t)N * 4);
    int*   cursor = (int*)alloc((size_t)N * 4);
    int*   offs   = (int*)alloc((size_t)(N + 1) * 4);
    int*   bsums  = (int*)alloc(256 * 4);
    int*   csr_src= (int*)alloc((size_t)E * 4);
    float* csr_w  = (float*)alloc((size_t)E * 4);
    float* hbuf   = (float*)alloc((size_t)N * 128 * 4);
    float* abuf   = (float*)alloc((size_t)N * 128 * 4);
    float* pooled = (float*)alloc((size_t)G * 128 * 4);

    int nbN = (N + 255) / 256;
    int nbE = (E + 255) / 256;
    k_init<<<nbN, 256, 0, stream>>>(deg, counts, cursor, N, pooled, G * 128);
    k_deg_hist<<<nbE, 256, 0, stream>>>(col, ew, deg, counts, E);
    k_dinv<<<nbN, 256, 0, stream>>>(deg, dinv, N);
    int sb = (N + 1023) / 1024;
    k_scan1<<<sb, 256, 0, stream>>>(counts, offs, bsums, N);
    k_scan2<<<1, 64, 0, stream>>>(bsums, offs, sb, N);
    k_scan3<<<nbN, 256, 0, stream>>>(offs, bsums, N);
    k_scatter<<<nbE, 256, 0, stream>>>(row, col, ew, dinv, offs, cursor, csr_src, csr_w, E);

    int gb = (N + 63) / 64;
    int ab = ((size_t)N * 64 + 255) / 256;
    k_gemm<<<gb, 256, 0, stream>>>(x, W1, hbuf, N);
    k_agg<<<ab, 256, 0, stream>>>(hbuf, abuf, offs, csr_src, csr_w, dinv, b1, N);
    k_gemm<<<gb, 256, 0, stream>>>(abuf, W2, hbuf, N);
    k_agg<<<ab, 256, 0, stream>>>(hbuf, abuf, offs, csr_src, csr_w, dinv, b2, N);
    k_pool<<<(N + 63) / 64, 128, 0, stream>>>(hbuf /*unused slot*/, batch, pooled, 0); // no-op guard
    k_pool<<<(N + 63) / 64, 128, 0, stream>>>(abuf, batch, pooled, N);
    k_mlp<<<G, 128, 0, stream>>>(pooled, batch, l1w, l1b, l2w, l2b, out, N, G);
}

// Round 4
// 503.955 us; speedup vs baseline: 1.5007x; 1.0271x over previous
//
#include <hip/hip_runtime.h>

// GCN: 2x GCNConv(128->128) + mean-pool + MLP(128->128->2), fp32.
// R3: k_gemm — out-dim split across blockIdx.y: 128 nodes x 64 outs per block,
// 32 KB LDS (64 W rows) -> 4 blocks/CU (was 2), og=t>>5 makes sW reads 2-way
// bank-aliased (free) instead of 4-way. k_agg unrolled 8x. Stray dispatch cut.

__global__ void k_init(float* deg, int* counts, int* cursor, int N,
                       float* pooled, int M) {
    int i = blockIdx.x * blockDim.x + threadIdx.x;
    if (i < N) { deg[i] = 1.0f; counts[i] = 0; cursor[i] = 0; }  // self-loop weight 1
    if (i < M) pooled[i] = 0.f;
}

__global__ void k_deg_hist(const int* __restrict__ col, const float* __restrict__ ew,
                           float* deg, int* counts, int E) {
    int e = blockIdx.x * blockDim.x + threadIdx.x;
    if (e < E) {
        int c = col[e];
        atomicAdd(&deg[c], ew[e]);
        atomicAdd(&counts[c], 1);
    }
}

__global__ void k_dinv(const float* __restrict__ deg, float* dinv, int N) {
    int i = blockIdx.x * blockDim.x + threadIdx.x;
    if (i < N) { float d = deg[i]; dinv[i] = d > 0.f ? rsqrtf(d) : 0.f; }
}

// --- 3-kernel exclusive scan over counts[N] -> offs[N+1] ---
__global__ void k_scan1(const int* __restrict__ counts, int* __restrict__ offs,
                        int* __restrict__ bsums, int N) {
    __shared__ int lds[256];
    int t = threadIdx.x;
    int base = blockIdx.x * 1024 + t * 4;
    int a0 = 0, a1 = 0, a2 = 0, a3 = 0;
    if (base + 3 < N) {
        int4 v = *(const int4*)(counts + base);
        a0 = v.x; a1 = v.y; a2 = v.z; a3 = v.w;
    } else {
        if (base + 0 < N) a0 = counts[base + 0];
        if (base + 1 < N) a1 = counts[base + 1];
        if (base + 2 < N) a2 = counts[base + 2];
        if (base + 3 < N) a3 = counts[base + 3];
    }
    int tsum = a0 + a1 + a2 + a3;
    lds[t] = tsum;
    __syncthreads();
    for (int d = 1; d < 256; d <<= 1) {
        int v = (t >= d) ? lds[t - d] : 0;
        __syncthreads();
        lds[t] += v;
        __syncthreads();
    }
    int excl = lds[t] - tsum;
    if (base + 0 < N) offs[base + 0] = excl;
    if (base + 1 < N) offs[base + 1] = excl + a0;
    if (base + 2 < N) offs[base + 2] = excl + a0 + a1;
    if (base + 3 < N) offs[base + 3] = excl + a0 + a1 + a2;
    if (t == 255) bsums[blockIdx.x] = lds[255];
}

__global__ void k_scan2(int* bsums, int* offs, int nb, int N) {
    if (threadIdx.x == 0 && blockIdx.x == 0) {
        int run = 0;
        for (int i = 0; i < nb; ++i) { int v = bsums[i]; bsums[i] = run; run += v; }
        offs[N] = run;
    }
}

__global__ void k_scan3(int* offs, const int* __restrict__ bsums, int N) {
    int i = blockIdx.x * blockDim.x + threadIdx.x;
    if (i < N) offs[i] += bsums[i >> 10];
}

__global__ void k_scatter(const int* __restrict__ row, const int* __restrict__ col,
                          const float* __restrict__ ew, const float* __restrict__ dinv,
                          const int* __restrict__ offs, int* cursor,
                          int* __restrict__ csr_src, float* __restrict__ csr_w, int E) {
    int e = blockIdx.x * blockDim.x + threadIdx.x;
    if (e < E) {
        int r = row[e], c = col[e];
        float w = dinv[r] * ew[e] * dinv[c];
        int pos = offs[c] + atomicAdd(&cursor[c], 1);
        csr_src[pos] = r;
        csr_w[pos] = w;
    }
}

// Y[n][o] = sum_k X[n][k] * W[o][k]  (h = x @ W.T), fp32 vector ALU.
// Grid (ceil(N/128), 2): blockIdx.y picks a 64-out half; 64 W rows in 32 KB
// LDS -> 4 blocks/CU, 16 waves/CU. 256 thr = 8 og (t>>5, 8 outs) x 32 ng
// (t&31, 4 nodes). Wave spans 2 og values -> sW reads 2-way aliased = free.
__global__ __launch_bounds__(256, 4) void k_gemm(const float* __restrict__ X,
                                                 const float* __restrict__ W,
                                                 float* __restrict__ Y, int N) {
    __shared__ float sW[64 * 128];   // 32 KB
    int t = threadIdx.x;
    int obase = blockIdx.y * 64;
    {
        const float4* src = (const float4*)(W + (size_t)obase * 128);
        float4* dst = (float4*)sW;
#pragma unroll
        for (int i = 0; i < 8; ++i)
            dst[t + 256 * i] = src[t + 256 * i];
    }
    __syncthreads();

    int og = t >> 5;          // 0..7  -> 8 outs each (within 64-out half)
    int ng = t & 31;          // 0..31 -> 4 nodes each
    int nbase = blockIdx.x * 128 + ng * 4;
    int ob = og * 8;
    float acc[4][8];
#pragma unroll
    for (int i = 0; i < 4; ++i)
#pragma unroll
        for (int j = 0; j < 8; ++j) acc[i][j] = 0.f;
    bool v[4];
#pragma unroll
    for (int i = 0; i < 4; ++i) v[i] = (nbase + i) < N;

#pragma unroll 2
    for (int k = 0; k < 128; k += 4) {
        float4 xv[4];
#pragma unroll
        for (int i = 0; i < 4; ++i)
            xv[i] = v[i] ? *(const float4*)(X + (size_t)(nbase + i) * 128 + k)
                         : make_float4(0.f, 0.f, 0.f, 0.f);
        float4 wv[8];
#pragma unroll
        for (int j = 0; j < 8; ++j)
            wv[j] = *(const float4*)(sW + (ob + j) * 128 + k);
#pragma unroll
        for (int i = 0; i < 4; ++i)
#pragma unroll
            for (int j = 0; j < 8; ++j)
                acc[i][j] += xv[i].x * wv[j].x + xv[i].y * wv[j].y +
                             xv[i].z * wv[j].z + xv[i].w * wv[j].w;
    }
#pragma unroll
    for (int i = 0; i < 4; ++i) {
        if (v[i]) {
            float* dst = Y + (size_t)(nbase + i) * 128 + obase + ob;
            *(float4*)dst       = make_float4(acc[i][0], acc[i][1], acc[i][2], acc[i][3]);
            *(float4*)(dst + 4) = make_float4(acc[i][4], acc[i][5], acc[i][6], acc[i][7]);
        }
    }
}

// One wave per node. wid wave-uniform -> offs/csr reads are scalar (s_load);
// edge loop unrolled 8x -> 8 independent 512B row-gathers in flight per wave.
__global__ __launch_bounds__(256) void k_agg(const float* __restrict__ H, float* __restrict__ O,
                                             const int* __restrict__ offs,
                                             const int* __restrict__ csr_src,
                                             const float* __restrict__ csr_w,
                                             const float* __restrict__ dinv,
                                             const float* __restrict__ bias, int N) {
    int wid = __builtin_amdgcn_readfirstlane((blockIdx.x * blockDim.x + threadIdx.x) >> 6);
    int lane = threadIdx.x & 63;
    if (wid >= N) return;
    const float2* H2 = (const float2*)H;
    float di = dinv[wid];
    float sw = di * di;
    float2 h0 = H2[(size_t)wid * 64 + lane];
    float ax = sw * h0.x, ay = sw * h0.y;
    int s = offs[wid], e = offs[wid + 1];
    int j = s;
    for (; j + 8 <= e; j += 8) {
        int   s0 = csr_src[j],   s1 = csr_src[j+1], s2 = csr_src[j+2], s3 = csr_src[j+3];
        int   s4 = csr_src[j+4], s5 = csr_src[j+5], s6 = csr_src[j+6], s7 = csr_src[j+7];
        float w0 = csr_w[j],     w1 = csr_w[j+1],   w2 = csr_w[j+2],   w3 = csr_w[j+3];
        float w4 = csr_w[j+4],   w5 = csr_w[j+5],   w6 = csr_w[j+6],   w7 = csr_w[j+7];
        float2 a0 = H2[(size_t)s0 * 64 + lane];
        float2 a1 = H2[(size_t)s1 * 64 + lane];
        float2 a2 = H2[(size_t)s2 * 64 + lane];
        float2 a3 = H2[(size_t)s3 * 64 + lane];
        float2 a4 = H2[(size_t)s4 * 64 + lane];
        float2 a5 = H2[(size_t)s5 * 64 + lane];
        float2 a6 = H2[(size_t)s6 * 64 + lane];
        float2 a7 = H2[(size_t)s7 * 64 + lane];
        ax += w0 * a0.x; ay += w0 * a0.y;
        ax += w1 * a1.x; ay += w1 * a1.y;
        ax += w2 * a2.x; ay += w2 * a2.y;
        ax += w3 * a3.x; ay += w3 * a3.y;
        ax += w4 * a4.x; ay += w4 * a4.y;
        ax += w5 * a5.x; ay += w5 * a5.y;
        ax += w6 * a6.x; ay += w6 * a6.y;
        ax += w7 * a7.x; ay += w7 * a7.y;
    }
    for (; j < e; ++j) {
        int ss = csr_src[j];
        float ww = csr_w[j];
        float2 hv = H2[(size_t)ss * 64 + lane];
        ax += ww * hv.x; ay += ww * hv.y;
    }
    float2 bb = ((const float2*)bias)[lane];
    ax = fmaxf(ax + bb.x, 0.f);
    ay = fmaxf(ay + bb.y, 0.f);
    ((float2*)O)[(size_t)wid * 64 + lane] = make_float2(ax, ay);
}

// Parallel mean-pool stage 1: each block sums 64 consecutive (batch-sorted)
// nodes per feature column, one atomicAdd per graph segment.
__global__ __launch_bounds__(128) void k_pool(const float* __restrict__ H,
                                              const int* __restrict__ batch,
                                              float* __restrict__ pooled, int N) {
    int t = threadIdx.x;
    int n0 = blockIdx.x * 64;
    if (n0 >= N) return;
    int n1 = min(n0 + 64, N);
    int cur = batch[n0];
    float acc = 0.f;
    for (int n = n0; n < n1; ++n) {
        int g = batch[n];
        if (g != cur) {
            atomicAdd(&pooled[cur * 128 + t], acc);
            acc = 0.f; cur = g;
        }
        acc += H[(size_t)n * 128 + t];
    }
    atomicAdd(&pooled[cur * 128 + t], acc);
}

// Stage 2: divide by count (binary search over sorted batch) + MLP.
__global__ __launch_bounds__(128) void k_mlp(const float* __restrict__ pooled,
                                             const int* __restrict__ batch,
                                             const float* __restrict__ w1,
                                             const float* __restrict__ b1,
                                             const float* __restrict__ w2,
                                             const float* __restrict__ b2,
                                             float* __restrict__ out, int N, int G) {
    __shared__ float pl[128];
    __shared__ float h1[128];
    int g = blockIdx.x, t = threadIdx.x;
    int lo = 0, hi = N;
    while (lo < hi) { int m = (lo + hi) >> 1; if (batch[m] < g) lo = m + 1; else hi = m; }
    int s = lo;
    lo = s; hi = N;
    while (lo < hi) { int m = (lo + hi) >> 1; if (batch[m] < g + 1) lo = m + 1; else hi = m; }
    float cnt = (float)(lo - s);
    pl[t] = pooled[g * 128 + t] / fmaxf(cnt, 1.0f);
    __syncthreads();
    float sum = b1[t];
#pragma unroll 4
    for (int k = 0; k < 128; ++k) sum += w1[t * 128 + k] * pl[k];
    h1[t] = fmaxf(sum, 0.f);
    __syncthreads();
    if (t < 2) {
        float s2 = b2[t];
        for (int k = 0; k < 128; ++k) s2 += w2[t * 128 + k] * h1[k];
        out[g * 2 + t] = s2;
    }
}

extern "C" void kernel_launch(void* const* d_in, const int* in_sizes, int n_in,
                              void* d_out, int out_size, void* d_ws, size_t ws_size,
                              hipStream_t stream) {
    const float* x   = (const float*)d_in[0];
    const int*   ei  = (const int*)d_in[1];
    const float* ew  = (const float*)d_in[2];
    const int* batch = (const int*)d_in[3];
    const float* W1  = (const float*)d_in[4];
    const float* b1  = (const float*)d_in[5];
    const float* W2  = (const float*)d_in[6];
    const float* b2  = (const float*)d_in[7];
    const float* l1w = (const float*)d_in[8];
    const float* l1b = (const float*)d_in[9];
    const float* l2w = (const float*)d_in[10];
    const float* l2b = (const float*)d_in[11];
    float* out = (float*)d_out;

    const int E = in_sizes[2];   // edge_weight count
    const int N = in_sizes[3];   // batch count = nodes
    const int G = out_size / 2;
    const int* row = ei;
    const int* col = ei + E;

    char* p = (char*)d_ws;
    auto alloc = [&](size_t bytes) -> void* {
        void* r = (void*)p;
        p += (bytes + 511) & ~(size_t)511;
        return r;
    };
    float* deg    = (float*)alloc((size_t)N * 4);
    float* dinv   = (float*)alloc((size_t)N * 4);
    int*   counts = (int*)alloc((size_t)N * 4);
    int*   cursor = (int*)alloc((size_t)N * 4);
    int*   offs   = (int*)alloc((size_t)(N + 1) * 4);
    int*   bsums  = (int*)alloc(256 * 4);
    int*   csr_src= (int*)alloc((size_t)E * 4);
    float* csr_w  = (float*)alloc((size_t)E * 4);
    float* hbuf   = (float*)alloc((size_t)N * 128 * 4);
    float* abuf   = (float*)alloc((size_t)N * 128 * 4);
    float* pooled = (float*)alloc((size_t)G * 128 * 4);

    int nbN = (N + 255) / 256;
    int nbE = (E + 255) / 256;
    k_init<<<nbN, 256, 0, stream>>>(deg, counts, cursor, N, pooled, G * 128);
    k_deg_hist<<<nbE, 256, 0, stream>>>(col, ew, deg, counts, E);
    k_dinv<<<nbN, 256, 0, stream>>>(deg, dinv, N);
    int sb = (N + 1023) / 1024;
    k_scan1<<<sb, 256, 0, stream>>>(counts, offs, bsums, N);
    k_scan2<<<1, 64, 0, stream>>>(bsums, offs, sb, N);
    k_scan3<<<nbN, 256, 0, stream>>>(offs, bsums, N);
    k_scatter<<<nbE, 256, 0, stream>>>(row, col, ew, dinv, offs, cursor, csr_src, csr_w, E);

    dim3 gg((N + 127) / 128, 2);
    int ab = ((size_t)N * 64 + 255) / 256;
    k_gemm<<<gg, 256, 0, stream>>>(x, W1, hbuf, N);
    k_agg<<<ab, 256, 0, stream>>>(hbuf, abuf, offs, csr_src, csr_w, dinv, b1, N);
    k_gemm<<<gg, 256, 0, stream>>>(abuf, W2, hbuf, N);
    k_agg<<<ab, 256, 0, stream>>>(hbuf, abuf, offs, csr_src, csr_w, dinv, b2, N);
    k_pool<<<(N + 63) / 64, 128, 0, stream>>>(abuf, batch, pooled, N);
    k_mlp<<<G, 128, 0, stream>>>(pooled, batch, l1w, l1b, l2w, l2b, out, N, G);
}